// Round 6
// baseline (533.363 us; speedup 1.0000x reference)
//
#include <hip/hip_runtime.h>

typedef unsigned short ushort_t;
typedef __bf16 bf16x8 __attribute__((ext_vector_type(8)));
typedef float floatx4 __attribute__((ext_vector_type(4)));
typedef ushort_t ushortx8 __attribute__((ext_vector_type(8)));
typedef ushort_t ushortx4 __attribute__((ext_vector_type(4)));

#define BM 128
#define BN 128
#define BKK 64

__device__ __forceinline__ ushort_t f2bf(float f) {
  union { float f; unsigned int u; } c; c.f = f;
  unsigned int r = c.u + 0x7FFFu + ((c.u >> 16) & 1u);
  return (ushort_t)(r >> 16);
}

__device__ __forceinline__ float bf2f(ushort_t u) {
  union { unsigned int u; float f; } c; c.u = ((unsigned int)u) << 16;
  return c.f;
}

// Async 16B global->LDS (lane-contiguous LDS dest required: base + lane*16).
__device__ __forceinline__ void async16(const ushort_t* g, ushort_t* l) {
  __builtin_amdgcn_global_load_lds(
      (const __attribute__((address_space(1))) unsigned int*)g,
      (__attribute__((address_space(3))) unsigned int*)l, 16, 0, 0);
}

// ============================================================================
// Shared 256x256 8-phase K-loop core (m201 template: T2 LDS swizzle + T3/T4
// counted vmcnt + T5 setprio). 812 TF measured at K=1024 == 96% of the known
// plain-HIP ceiling for this regime (m248: 848 TF) -- do not touch.
// ============================================================================
__device__ __forceinline__ void gemm_core(
    const ushort_t* __restrict__ gA, const ushort_t* __restrict__ gB,
    int lda, int ldb, int K,
    ushort_t (&As)[2][256][64], ushort_t (&Bs)[2][256][64],
    const int srow, const int dcb, const int wm, const int wn,
    const int l15, const int pb0, const int pb1,
    floatx4 (&acc)[8][4])
{
  bf16x8 aA[4][2], bB0[2][2], bB1[2][2];
  const int NT = K >> 6;   // K-tiles of 64
  const int NI = NT >> 1;  // iterations (2 tiles each)

#define STAGE_A(sl, hf, kt) do { \
    const ushort_t* _s = gA + (long)((hf) * 128) * lda + ((kt) << 6); \
    async16(_s,                  &As[sl][(hf)*128      + srow][dcb]); \
    async16(_s + (long)64 * lda, &As[sl][(hf)*128 + 64 + srow][dcb]); \
  } while (0)
#define STAGE_B(sl, hf, kt) do { \
    const ushort_t* _s = gB + (long)((hf) * 128) * ldb + ((kt) << 6); \
    async16(_s,                  &Bs[sl][(hf)*128      + srow][dcb]); \
    async16(_s + (long)64 * ldb, &Bs[sl][(hf)*128 + 64 + srow][dcb]); \
  } while (0)
#define LD_A(sl, mh) do { \
    _Pragma("unroll") for (int _i = 0; _i < 4; ++_i) { \
      const int _r = wm*128 + (mh)*64 + _i*16 + l15; \
      aA[_i][0] = *(const bf16x8*)&As[sl][_r][pb0]; \
      aA[_i][1] = *(const bf16x8*)&As[sl][_r][pb1]; } \
  } while (0)
#define LD_B(sl, nh, dst) do { \
    _Pragma("unroll") for (int _j = 0; _j < 2; ++_j) { \
      const int _r = wn*64 + (nh)*32 + _j*16 + l15; \
      dst[_j][0] = *(const bf16x8*)&Bs[sl][_r][pb0]; \
      dst[_j][1] = *(const bf16x8*)&Bs[sl][_r][pb1]; } \
  } while (0)
#define MMA(mh, nh, bfr) do { \
    __builtin_amdgcn_s_setprio(1); \
    _Pragma("unroll") for (int _i = 0; _i < 4; ++_i) \
    _Pragma("unroll") for (int _j = 0; _j < 2; ++_j) { \
      floatx4& _c = acc[(mh)*4 + _i][(nh)*2 + _j]; \
      _c = __builtin_amdgcn_mfma_f32_16x16x32_bf16(aA[_i][0], (bfr)[_j][0], _c, 0, 0, 0); \
      _c = __builtin_amdgcn_mfma_f32_16x16x32_bf16(aA[_i][1], (bfr)[_j][1], _c, 0, 0, 0); } \
    __builtin_amdgcn_s_setprio(0); \
  } while (0)
#define SBAR  __builtin_amdgcn_s_barrier()
#define LGKM0 asm volatile("s_waitcnt lgkmcnt(0)" ::: "memory")
#define VM4   asm volatile("s_waitcnt vmcnt(4)" ::: "memory")
#define VM0   asm volatile("s_waitcnt vmcnt(0)" ::: "memory")

  // Prologue: tile0 (4 halves) + A0(1), B1(1).
  STAGE_A(0, 0, 0); STAGE_A(0, 1, 0); STAGE_B(0, 0, 0); STAGE_B(0, 1, 0);
  STAGE_A(1, 0, 1); STAGE_B(1, 1, 1);
  VM4; SBAR;

  for (int i = 0; i < NI - 1; ++i) {
    const int t1 = 2*i + 1, t2 = 2*i + 2, t3 = 2*i + 3;
    LD_A(0, 0); LD_B(0, 0, bB0); STAGE_A(1, 1, t1);
    SBAR; LGKM0; MMA(0, 0, bB0); SBAR;
    LD_B(0, 1, bB1); STAGE_B(1, 0, t1);
    SBAR; LGKM0; MMA(0, 1, bB1); SBAR;
    LD_A(0, 1); STAGE_A(0, 0, t2);
    SBAR; LGKM0; MMA(1, 1, bB1); SBAR;
    STAGE_B(0, 1, t2);
    SBAR; LGKM0; MMA(1, 0, bB0); VM4; SBAR;
    LD_A(1, 0); LD_B(1, 0, bB0); STAGE_A(0, 1, t2);
    SBAR; LGKM0; MMA(0, 0, bB0); SBAR;
    LD_B(1, 1, bB1); STAGE_B(0, 0, t2);
    SBAR; LGKM0; MMA(0, 1, bB1); SBAR;
    LD_A(1, 1); STAGE_A(1, 0, t3);
    SBAR; LGKM0; MMA(1, 1, bB1); SBAR;
    STAGE_B(1, 1, t3);
    SBAR; LGKM0; MMA(1, 0, bB0); VM4; SBAR;
  }
  // Peeled final iteration.
  {
    const int t1 = NT - 1;
    LD_A(0, 0); LD_B(0, 0, bB0); STAGE_A(1, 1, t1);
    SBAR; LGKM0; MMA(0, 0, bB0); SBAR;
    LD_B(0, 1, bB1); STAGE_B(1, 0, t1);
    SBAR; LGKM0; MMA(0, 1, bB1); SBAR;
    LD_A(0, 1);
    SBAR; LGKM0; MMA(1, 1, bB1); SBAR;
    SBAR; LGKM0; MMA(1, 0, bB0); VM0; SBAR;
    LD_A(1, 0); LD_B(1, 0, bB0);
    SBAR; LGKM0; MMA(0, 0, bB0); SBAR;
    LD_B(1, 1, bB1);
    SBAR; LGKM0; MMA(0, 1, bB1); SBAR;
    LD_A(1, 1);
    SBAR; LGKM0; MMA(1, 1, bB1); SBAR;
    LGKM0; MMA(1, 0, bB0);
  }
#undef STAGE_A
#undef STAGE_B
#undef LD_A
#undef LD_B
#undef MMA
#undef SBAR
#undef LGKM0
#undef VM4
#undef VM0
}

// ============================================================================
// Fused Q + KV projection (256^2 8-phase), K=1024, 48 tiles/z = 768 blocks.
// ============================================================================
__global__ __launch_bounds__(512, 2)
void gemm_qkv(const ushort_t* __restrict__ xT, const ushort_t* __restrict__ Wq_b,
              ushort_t* __restrict__ Qt, ushort_t* __restrict__ KV,
              const float* __restrict__ bq, const float* __restrict__ bkv)
{
  __shared__ ushort_t As[2][256][64];
  __shared__ ushort_t Bs[2][256][64];

  const int z = blockIdx.z;
  const int id = blockIdx.x;
  const bool isQ = id < 16;
  const int bx = isQ ? (id & 1) : ((id - 16) & 7);
  const int by = isQ ? (id >> 1) : ((id - 16) >> 3);
  const int m0 = by * 256;
  const int n0 = bx * 256;
  const ushort_t* xz = xT + (long)z * 2048 * 1024;
  const ushort_t* Abase = isQ ? xz : (Wq_b + 512 * 1024);  // Wkv rows follow Wq
  const ushort_t* Bbase = isQ ? Wq_b : xz;

  const int tid = threadIdx.x;
  const int lane = tid & 63;
  const int wid = tid >> 6;
  const int wm = wid >> 2;
  const int wn = wid & 3;
  const int l15 = lane & 15;
  const int lq  = lane >> 4;
  const int srow = tid >> 3;
  const int scb  = (((tid & 7) ^ (srow & 7)) << 3);
  const int dcb  = (tid & 7) << 3;
  const int pb0 = ((lq ^ (l15 & 7)) << 3);
  const int pb1 = (((4 | lq) ^ (l15 & 7)) << 3);

  const ushort_t* gA = Abase + (long)(m0 + srow) * 1024 + scb;
  const ushort_t* gB = Bbase + (long)(n0 + srow) * 1024 + scb;

  floatx4 acc[8][4];
#pragma unroll
  for (int i = 0; i < 8; ++i)
#pragma unroll
    for (int j = 0; j < 4; ++j)
#pragma unroll
      for (int r = 0; r < 4; ++r) acc[i][j][r] = 0.0f;

  gemm_core(gA, gB, 1024, 1024, 1024, As, Bs, srow, dcb, wm, wn, l15, pb0, pb1, acc);

  if (isQ) {
    ushort_t* Cq = Qt + (long)z * 2048 * 512;
#pragma unroll
    for (int mi = 0; mi < 8; ++mi) {
      const int mbase = m0 + wm*128 + (mi >> 2)*64 + (mi & 3)*16 + lq*4;
#pragma unroll
      for (int nj = 0; nj < 4; ++nj) {
        const int n = n0 + wn*64 + (nj >> 1)*32 + (nj & 1)*16 + l15;
        const float bn_ = bq[n];
#pragma unroll
        for (int r = 0; r < 4; ++r)
          Cq[(long)(mbase + r) * 512 + n] = f2bf(acc[mi][nj][r] + bn_);
      }
    }
  } else {
    ushort_t* Ckv = KV + (long)z * 1024 * 1024;
#pragma unroll
    for (int mi = 0; mi < 8; ++mi) {
      const int mbase = m0 + wm*128 + (mi >> 2)*64 + (mi & 3)*16 + lq*4;
#pragma unroll
      for (int nj = 0; nj < 4; ++nj) {
        const int n = n0 + wn*64 + (nj >> 1)*32 + (nj & 1)*16 + l15;
#pragma unroll
        for (int r = 0; r < 4; ++r) {
          float v = acc[mi][nj][r] + bkv[mbase + r];
          float o = __shfl_xor(v, 1);
          float w = fmaxf(v, o);
          if ((lane & 1) == 0)
            Ckv[(long)(mbase + r) * 1024 + (n >> 1)] = f2bf(w);
        }
      }
    }
  }
}

// ============================================================================
// 128x128 GEMM (m97 structure): 32 KiB LDS -> 3-4 blocks/CU TLP hides barrier
// stalls (m114 mechanism). Used for all K<=1024 / small-grid GEMMs.
// STATS: per-channel(m) sum/sumsq -> pstat[(z*gridDim.x+bx)*1024 + m].
// ============================================================================
template<int BIASM, int POOLM, bool OUTF32, bool STATS = false>
__global__ __launch_bounds__(256)
void gemm_bt(const ushort_t* __restrict__ A, long aStr,
             const ushort_t* __restrict__ B, long bStr,
             void* __restrict__ Cp, long cStr,
             int K, int lda, int ldb, int ldc,
             const float* __restrict__ bias, float scale,
             float2* __restrict__ pstat = nullptr)
{
  __shared__ ushort_t As[BM][BKK];
  __shared__ ushort_t Bs[BN][BKK];
  __shared__ float2 part2[2][128];   // STATS only: wn-halves per channel
  A += (long)blockIdx.z * aStr;
  B += (long)blockIdx.z * bStr;
  float* Cf = (float*)Cp + (OUTF32 ? (long)blockIdx.z * cStr : 0);
  ushort_t* Cb = (ushort_t*)Cp + (OUTF32 ? 0 : (long)blockIdx.z * cStr);
  const int m0 = blockIdx.y * BM;
  const int n0 = blockIdx.x * BN;
  const int tid = threadIdx.x;
  const int lane = tid & 63;
  const int wm = (tid >> 7) & 1;
  const int wn = (tid >> 6) & 1;
  const int ar = tid >> 3;
  const int ac = (tid & 7) * 8;

  floatx4 acc[4][4];
#pragma unroll
  for (int i = 0; i < 4; ++i)
#pragma unroll
    for (int j = 0; j < 4; ++j)
#pragma unroll
      for (int r = 0; r < 4; ++r) acc[i][j][r] = 0.0f;

  const int q8 = (lane >> 4) * 8;
  const int l15 = lane & 15;
  const int lq = lane >> 4;

  const ushort_t* gA = &A[(long)(m0 + ar) * lda + ac];
  const ushort_t* gB = &B[(long)(n0 + ar) * ldb + ac];
  const long aRow32 = (long)32 * lda;
  const long bRow32 = (long)32 * ldb;

  for (int k0 = 0; k0 < K; k0 += BKK) {
#pragma unroll
    for (int p = 0; p < 4; ++p)
      async16(gA + p * aRow32 + k0, &As[p * 32 + ar][ac]);
#pragma unroll
    for (int p = 0; p < 4; ++p)
      async16(gB + p * bRow32 + k0, &Bs[p * 32 + ar][ac]);
    __syncthreads();
#pragma unroll
    for (int kk = 0; kk < 2; ++kk) {
      const int kr = kk * 32 + q8;
      bf16x8 af[4], bfr[4];
#pragma unroll
      for (int i = 0; i < 4; ++i) {
        af[i]  = *(const bf16x8*)(&As[wm * 64 + i * 16 + l15][kr]);
        bfr[i] = *(const bf16x8*)(&Bs[wn * 64 + i * 16 + l15][kr]);
      }
#pragma unroll
      for (int i = 0; i < 4; ++i)
#pragma unroll
        for (int j = 0; j < 4; ++j)
          acc[i][j] = __builtin_amdgcn_mfma_f32_16x16x32_bf16(af[i], bfr[j], acc[i][j], 0, 0, 0);
    }
    __syncthreads();
  }

#pragma unroll
  for (int i = 0; i < 4; ++i) {
    const int mbase = m0 + wm * 64 + i * 16 + lq * 4;
    float ss[4], ss2[4];
    if (STATS) {
#pragma unroll
      for (int r = 0; r < 4; ++r) { ss[r] = 0.0f; ss2[r] = 0.0f; }
    }
#pragma unroll
    for (int j = 0; j < 4; ++j) {
      const int n = n0 + wn * 64 + j * 16 + l15;
      float v[4];
#pragma unroll
      for (int r = 0; r < 4; ++r) {
        v[r] = acc[i][j][r] * scale;
        if (BIASM == 1) v[r] += bias[mbase + r];
      }
      if (BIASM == 2) {
        const float bn_ = bias[n];
#pragma unroll
        for (int r = 0; r < 4; ++r) v[r] += bn_;
      }
      if (STATS) {
#pragma unroll
        for (int r = 0; r < 4; ++r) { ss[r] += v[r]; ss2[r] += v[r] * v[r]; }
      }
      if (POOLM == 0) {
#pragma unroll
        for (int r = 0; r < 4; ++r) {
          if (OUTF32) Cf[(long)(mbase + r) * ldc + n] = v[r];
          else        Cb[(long)(mbase + r) * ldc + n] = f2bf(v[r]);
        }
      } else if (POOLM == 1) {
#pragma unroll
        for (int r = 0; r < 4; ++r) {
          float o = __shfl_xor(v[r], 1);
          float w = fmaxf(v[r], o);
          if ((lane & 1) == 0) {
            if (OUTF32) Cf[(long)(mbase + r) * ldc + (n >> 1)] = w;
            else        Cb[(long)(mbase + r) * ldc + (n >> 1)] = f2bf(w);
          }
        }
      } else {
        float w0 = fmaxf(v[0], v[1]);
        float w1 = fmaxf(v[2], v[3]);
        const int mh = mbase >> 1;
        if (OUTF32) {
          Cf[(long)mh * ldc + n] = w0;
          Cf[(long)(mh + 1) * ldc + n] = w1;
        } else {
          Cb[(long)mh * ldc + n] = f2bf(w0);
          Cb[(long)(mh + 1) * ldc + n] = f2bf(w1);
        }
      }
    }
    if (STATS) {
      // Sum the 16 l15 lanes (same channel group, different n).
#pragma unroll
      for (int o = 1; o < 16; o <<= 1) {
#pragma unroll
        for (int r = 0; r < 4; ++r) {
          ss[r]  += __shfl_xor(ss[r],  o);
          ss2[r] += __shfl_xor(ss2[r], o);
        }
      }
      if (l15 == 0) {
        const int chb = wm * 64 + i * 16 + lq * 4;  // local channel 0..127
#pragma unroll
        for (int r = 0; r < 4; ++r) part2[wn][chb + r] = make_float2(ss[r], ss2[r]);
      }
    }
  }
  if (STATS) {
    __syncthreads();
    if (tid < 128) {
      float2 a = part2[0][tid], b = part2[1][tid];
      pstat[((long)blockIdx.z * gridDim.x + blockIdx.x) * 1024 + m0 + tid] =
          make_float2(a.x + b.x, a.y + b.y);
    }
  }
}

// ============================================================================
// Prologue union kernel: grid (32, 17, 16).
//  by < 16 : xT[t][c] = bf16(x[c][t]) transpose, 64x64 tiles (float4 reads,
//            ushort8 writes).
//  by == 16: weight fp32->bf16 convert (512 blocks x 256 thr x 16 elems) +
//            bkv concat (block cid==0).
// ============================================================================
__global__ __launch_bounds__(256)
void prolog(const float* __restrict__ x, ushort_t* __restrict__ xT,
            const float* __restrict__ Wq, const float* __restrict__ Wk,
            const float* __restrict__ Wv, const float* __restrict__ Wo,
            ushort_t* __restrict__ Wb,
            const float* __restrict__ bk, const float* __restrict__ bv,
            float* __restrict__ bkv)
{
  if (blockIdx.y == 16) {
    const int cid = blockIdx.z * 32 + blockIdx.x;         // 0..511
    const long base = (long)cid * 4096 + threadIdx.x * 16; // 16 elems/thread
    const float* srcs[4] = {Wq, Wk, Wv, Wo};
    const float* s = srcs[base >> 19];                     // 524288 elems each
    const long off = base & 524287;
#pragma unroll
    for (int p = 0; p < 4; ++p) {
      floatx4 v = *(const floatx4*)&s[off + p * 4];
      ushortx4 o;
#pragma unroll
      for (int r = 0; r < 4; ++r) o[r] = f2bf(v[r]);
      *(ushortx4*)&Wb[base + p * 4] = o;
    }
    if (cid == 0) {
      for (int j = threadIdx.x; j < 1024; j += 256)
        bkv[j] = (j < 512) ? bk[j] : bv[j - 512];
    }
    return;
  }
  __shared__ ushort_t tileT[64][72];
  const long boff = (long)blockIdx.z * 1024 * 2048;
  const int t0 = blockIdx.x * 64;
  const int r0 = blockIdx.y * 64;
  const int tx = threadIdx.x & 15;
  const int ty = threadIdx.x >> 4;
#pragma unroll
  for (int i = 0; i < 4; ++i) {
    const int c = ty + 16 * i;
    floatx4 v = *(const floatx4*)&x[boff + (long)(r0 + c) * 2048 + t0 + 4 * tx];
#pragma unroll
    for (int j = 0; j < 4; ++j) tileT[4 * tx + j][c] = f2bf(v[j]);
  }
  __syncthreads();
  const int cx = threadIdx.x & 7;
  const int tw = threadIdx.x >> 3;
#pragma unroll
  for (int i = 0; i < 2; ++i) {
    const int t = tw + 32 * i;
    ushortx8 w = *(const ushortx8*)&tileT[t][8 * cx];
    *(ushortx8*)&xT[boff + (long)(t0 + t) * 1024 + r0 + 8 * cx] = w;
  }
}

// out = gamma*(yb-mean)*rstd + beta + x ; per-block reduce of 256 L2-hot
// pstat partials for this channel, then streaming apply (float4).
__global__ __launch_bounds__(256)
void bn_apply(const ushort_t* __restrict__ yb, const float* __restrict__ x,
              float* __restrict__ out, const float2* __restrict__ pstat,
              const float* __restrict__ gamma, const float* __restrict__ beta)
{
  const int bc = blockIdx.x;
  const int c = bc & 1023;
  float2 p = pstat[(long)threadIdx.x * 1024 + c];  // 256 slots
  float s = p.x, s2 = p.y;
#pragma unroll
  for (int o = 32; o > 0; o >>= 1) { s += __shfl_down(s, o); s2 += __shfl_down(s2, o); }
  __shared__ float red[8];
  __shared__ float smv[2];
  const int w = threadIdx.x >> 6;
  if ((threadIdx.x & 63) == 0) { red[w] = s; red[4 + w] = s2; }
  __syncthreads();
  if (threadIdx.x == 0) {
    float ts = red[0] + red[1] + red[2] + red[3];
    float ts2 = red[4] + red[5] + red[6] + red[7];
    const float inv = 1.0f / (16.0f * 2048.0f);
    float mean = ts * inv;
    float var = ts2 * inv - mean * mean;
    smv[0] = mean;
    smv[1] = rsqrtf(var + 1e-5f);
  }
  __syncthreads();
  const float mean = smv[0];
  const float g = gamma[c] * smv[1];
  const float bt = beta[c];
  const long off = (long)bc * 2048;
  const ushortx8* yp = (const ushortx8*)(yb + off);
  const floatx4* xp = (const floatx4*)(x + off);
  floatx4* op = (floatx4*)(out + off);
  const int t = threadIdx.x;           // 256 threads x 8 elems = 2048
  ushortx8 v8 = yp[t];
  floatx4 x0 = xp[2 * t], x1 = xp[2 * t + 1];
  floatx4 o0, o1;
#pragma unroll
  for (int r = 0; r < 4; ++r) o0[r] = (bf2f(v8[r]) - mean) * g + bt + x0[r];
#pragma unroll
  for (int r = 0; r < 4; ++r) o1[r] = (bf2f(v8[4 + r]) - mean) * g + bt + x1[r];
  op[2 * t] = o0;
  op[2 * t + 1] = o1;
}

extern "C" void kernel_launch(void* const* d_in, const int* in_sizes, int n_in,
                              void* d_out, int out_size, void* d_ws, size_t ws_size,
                              hipStream_t stream) {
  (void)in_sizes; (void)n_in; (void)out_size; (void)ws_size;
  const float* x  = (const float*)d_in[0];
  const float* Wq = (const float*)d_in[1];
  const float* bq = (const float*)d_in[2];
  const float* Wk = (const float*)d_in[3];
  const float* bk = (const float*)d_in[4];
  const float* Wv = (const float*)d_in[5];
  const float* bv = (const float*)d_in[6];
  const float* Wo = (const float*)d_in[7];
  const float* bo = (const float*)d_in[8];
  const float* gamma = (const float*)d_in[9];
  const float* beta  = (const float*)d_in[10];
  float* out = (float*)d_out;

  const int Cc = 1024, T = 2048, D = 512, S = 1024;

  // Chain: prolog (transpose+convert) -> qkv (fused 256^2 8ph) ->
  // WtT = Kd V^T -> Wco = Wo WtT^T/T -> yb = bf16(Wco Qt^T + bo) with fused
  // BN partials (128^2 TLP kernel) -> bn_apply.
  ushort_t* ws   = (ushort_t*)d_ws;
  ushort_t* xT   = ws;                  // (B,T,C)  33,554,432
  ushort_t* Qt   = ws + 33554432;       // (B,T,D)  16,777,216
  ushort_t* KV   = ws + 50331648;       // (B,2D,S) 16,777,216
  ushort_t* WtT  = ws + 67108864;       // (B,D,D)   4,194,304
  ushort_t* Wco  = ws + 71303168;       // (B,C,D)   8,388,608
  ushort_t* yb   = ws + 79691776;       // (B,C,T)  33,554,432 bf16 pre-BN y
  ushort_t* Wq_b = ws + 113246208;      //  2,097,152 (Wq,Wk,Wv,Wo contiguous)
  ushort_t* Wo_b = ws + 113246208 + 3 * 524288;
  float*    bkv  = (float*)(ws + 115343360);    // 1024 floats
  float2*   pstat = (float2*)(ws + 115345408);  // 256*1024 float2 = 2 MB

  dim3 blk(256);
  dim3 blk512(512);

  // 0. Prologue: xT = bf16(x^T) (by<16) + weights->bf16 + bkv concat (by==16).
  prolog<<<dim3(32, 17, 16), blk, 0, stream>>>(x, xT, Wq, Wk, Wv, Wo, Wq_b,
                                               bk, bv, bkv);

  // 1. Fused Q + KV projection (768 blocks = 3 clean rounds).
  gemm_qkv<<<dim3(48, 1, 16), blk512, 0, stream>>>(xT, Wq_b, Qt, KV, bq, bkv);

  // 2. WtT (D,D) = Kd x V^T : K=S.
  gemm_bt<0, 0, false><<<dim3(D / 128, D / 128, 16), blk, 0, stream>>>(
      KV, (long)2 * D * S, KV + (long)D * S, (long)2 * D * S, WtT, (long)D * D,
      S, S, S, D, nullptr, 1.0f);
  // 3. Wco (C,D) = Wo x WtT^T / T : K=D.
  gemm_bt<0, 0, false><<<dim3(D / 128, Cc / 128, 16), blk, 0, stream>>>(
      Wo_b, 0, WtT, (long)D * D, Wco, (long)Cc * D,
      D, D, D, D, nullptr, 1.0f / 2048.0f);

  // 4. yb = bf16(Wco x Qt^T + bo), (B,C,T); fused BN partials.
  //    128^2 tiles: 2048 blocks, 3-4/CU TLP (was 256^2 @ 1/CU, NI=4).
  gemm_bt<1, 0, false, true><<<dim3(T / 128, Cc / 128, 16), blk, 0, stream>>>(
      Wco, (long)Cc * D, Qt, (long)T * D, yb, (long)Cc * T,
      D, D, D, T, bo, 1.0f, pstat);

  // 5. BN finalize (folded) + apply + residual -> fp32 out.
  bn_apply<<<dim3(16384), blk, 0, stream>>>(yb, x, out, pstat, gamma, beta);
}

// Round 7
// 510.139 us; speedup vs baseline: 1.0455x; 1.0455x over previous
//
#include <hip/hip_runtime.h>

typedef unsigned short ushort_t;
typedef __bf16 bf16x8 __attribute__((ext_vector_type(8)));
typedef float floatx4 __attribute__((ext_vector_type(4)));
typedef ushort_t ushortx8 __attribute__((ext_vector_type(8)));
typedef ushort_t ushortx4 __attribute__((ext_vector_type(4)));

#define BM 128
#define BN 128
#define BKK 64

__device__ __forceinline__ ushort_t f2bf(float f) {
  union { float f; unsigned int u; } c; c.f = f;
  unsigned int r = c.u + 0x7FFFu + ((c.u >> 16) & 1u);
  return (ushort_t)(r >> 16);
}

__device__ __forceinline__ float bf2f(ushort_t u) {
  union { unsigned int u; float f; } c; c.u = ((unsigned int)u) << 16;
  return c.f;
}

// Async 16B global->LDS (lane-contiguous LDS dest required: base + lane*16).
__device__ __forceinline__ void async16(const ushort_t* g, ushort_t* l) {
  __builtin_amdgcn_global_load_lds(
      (const __attribute__((address_space(1))) unsigned int*)g,
      (__attribute__((address_space(3))) unsigned int*)l, 16, 0, 0);
}

// ============================================================================
// Shared 256x256 8-phase K-loop core (m201 template: T2 LDS swizzle + T3/T4
// counted vmcnt + T5 setprio). 812 TF measured at K=1024 == 96% of the known
// plain-HIP ceiling for this regime (m248: 848 TF) -- do not touch.
// NOTE (R5 lesson): at K=512 this still beats the 128^2 m97 structure
// (~65-70us vs ~90us for the y-GEMM) -- do not retile small-K GEMMs to 128^2
// when the grid already fills the machine.
// ============================================================================
__device__ __forceinline__ void gemm_core(
    const ushort_t* __restrict__ gA, const ushort_t* __restrict__ gB,
    int lda, int ldb, int K,
    ushort_t (&As)[2][256][64], ushort_t (&Bs)[2][256][64],
    const int srow, const int dcb, const int wm, const int wn,
    const int l15, const int pb0, const int pb1,
    floatx4 (&acc)[8][4])
{
  bf16x8 aA[4][2], bB0[2][2], bB1[2][2];
  const int NT = K >> 6;   // K-tiles of 64
  const int NI = NT >> 1;  // iterations (2 tiles each)

#define STAGE_A(sl, hf, kt) do { \
    const ushort_t* _s = gA + (long)((hf) * 128) * lda + ((kt) << 6); \
    async16(_s,                  &As[sl][(hf)*128      + srow][dcb]); \
    async16(_s + (long)64 * lda, &As[sl][(hf)*128 + 64 + srow][dcb]); \
  } while (0)
#define STAGE_B(sl, hf, kt) do { \
    const ushort_t* _s = gB + (long)((hf) * 128) * ldb + ((kt) << 6); \
    async16(_s,                  &Bs[sl][(hf)*128      + srow][dcb]); \
    async16(_s + (long)64 * ldb, &Bs[sl][(hf)*128 + 64 + srow][dcb]); \
  } while (0)
#define LD_A(sl, mh) do { \
    _Pragma("unroll") for (int _i = 0; _i < 4; ++_i) { \
      const int _r = wm*128 + (mh)*64 + _i*16 + l15; \
      aA[_i][0] = *(const bf16x8*)&As[sl][_r][pb0]; \
      aA[_i][1] = *(const bf16x8*)&As[sl][_r][pb1]; } \
  } while (0)
#define LD_B(sl, nh, dst) do { \
    _Pragma("unroll") for (int _j = 0; _j < 2; ++_j) { \
      const int _r = wn*64 + (nh)*32 + _j*16 + l15; \
      dst[_j][0] = *(const bf16x8*)&Bs[sl][_r][pb0]; \
      dst[_j][1] = *(const bf16x8*)&Bs[sl][_r][pb1]; } \
  } while (0)
#define MMA(mh, nh, bfr) do { \
    __builtin_amdgcn_s_setprio(1); \
    _Pragma("unroll") for (int _i = 0; _i < 4; ++_i) \
    _Pragma("unroll") for (int _j = 0; _j < 2; ++_j) { \
      floatx4& _c = acc[(mh)*4 + _i][(nh)*2 + _j]; \
      _c = __builtin_amdgcn_mfma_f32_16x16x32_bf16(aA[_i][0], (bfr)[_j][0], _c, 0, 0, 0); \
      _c = __builtin_amdgcn_mfma_f32_16x16x32_bf16(aA[_i][1], (bfr)[_j][1], _c, 0, 0, 0); } \
    __builtin_amdgcn_s_setprio(0); \
  } while (0)
#define SBAR  __builtin_amdgcn_s_barrier()
#define LGKM0 asm volatile("s_waitcnt lgkmcnt(0)" ::: "memory")
#define VM4   asm volatile("s_waitcnt vmcnt(4)" ::: "memory")
#define VM0   asm volatile("s_waitcnt vmcnt(0)" ::: "memory")

  // Prologue: tile0 (4 halves) + A0(1), B1(1).
  STAGE_A(0, 0, 0); STAGE_A(0, 1, 0); STAGE_B(0, 0, 0); STAGE_B(0, 1, 0);
  STAGE_A(1, 0, 1); STAGE_B(1, 1, 1);
  VM4; SBAR;

  for (int i = 0; i < NI - 1; ++i) {
    const int t1 = 2*i + 1, t2 = 2*i + 2, t3 = 2*i + 3;
    LD_A(0, 0); LD_B(0, 0, bB0); STAGE_A(1, 1, t1);
    SBAR; LGKM0; MMA(0, 0, bB0); SBAR;
    LD_B(0, 1, bB1); STAGE_B(1, 0, t1);
    SBAR; LGKM0; MMA(0, 1, bB1); SBAR;
    LD_A(0, 1); STAGE_A(0, 0, t2);
    SBAR; LGKM0; MMA(1, 1, bB1); SBAR;
    STAGE_B(0, 1, t2);
    SBAR; LGKM0; MMA(1, 0, bB0); VM4; SBAR;
    LD_A(1, 0); LD_B(1, 0, bB0); STAGE_A(0, 1, t2);
    SBAR; LGKM0; MMA(0, 0, bB0); SBAR;
    LD_B(1, 1, bB1); STAGE_B(0, 0, t2);
    SBAR; LGKM0; MMA(0, 1, bB1); SBAR;
    LD_A(1, 1); STAGE_A(1, 0, t3);
    SBAR; LGKM0; MMA(1, 1, bB1); SBAR;
    STAGE_B(1, 1, t3);
    SBAR; LGKM0; MMA(1, 0, bB0); VM4; SBAR;
  }
  // Peeled final iteration.
  {
    const int t1 = NT - 1;
    LD_A(0, 0); LD_B(0, 0, bB0); STAGE_A(1, 1, t1);
    SBAR; LGKM0; MMA(0, 0, bB0); SBAR;
    LD_B(0, 1, bB1); STAGE_B(1, 0, t1);
    SBAR; LGKM0; MMA(0, 1, bB1); SBAR;
    LD_A(0, 1);
    SBAR; LGKM0; MMA(1, 1, bB1); SBAR;
    SBAR; LGKM0; MMA(1, 0, bB0); VM0; SBAR;
    LD_A(1, 0); LD_B(1, 0, bB0);
    SBAR; LGKM0; MMA(0, 0, bB0); SBAR;
    LD_B(1, 1, bB1);
    SBAR; LGKM0; MMA(0, 1, bB1); SBAR;
    LD_A(1, 1);
    SBAR; LGKM0; MMA(1, 1, bB1); SBAR;
    LGKM0; MMA(1, 0, bB0);
  }
#undef STAGE_A
#undef STAGE_B
#undef LD_A
#undef LD_B
#undef MMA
#undef SBAR
#undef LGKM0
#undef VM4
#undef VM0
}

// ============================================================================
// Generic 256^2 GEMM wrapper. BIASM: 0 none, 1 bias[m], 2 bias[n].
// POOLM: 0 none, 1 pool n-pairs, 2 pool m-pairs. OUTF32: write float.
// STATS: per-channel(m) sum/sumsq partials -> pstat (float2).
// ============================================================================
template<int BIASM, int POOLM, bool OUTF32, bool STATS = false>
__global__ __launch_bounds__(512, 2)
void gemm256(const ushort_t* __restrict__ A, long aStr,
             const ushort_t* __restrict__ B, long bStr,
             void* __restrict__ Cp, long cStr,
             int K, int lda, int ldb, int ldc,
             const float* __restrict__ bias, float scale,
             float2* __restrict__ pstat = nullptr)
{
  __shared__ ushort_t As[2][256][64];
  __shared__ ushort_t Bs[2][256][64];
  __shared__ float2 part[4][256];

  A += (long)blockIdx.z * aStr;
  B += (long)blockIdx.z * bStr;
  float* Cf = (float*)Cp + (OUTF32 ? (long)blockIdx.z * cStr : 0);
  ushort_t* Cb = (ushort_t*)Cp + (OUTF32 ? 0 : (long)blockIdx.z * cStr);
  const int m0 = blockIdx.y * 256;
  const int n0 = blockIdx.x * 256;
  const int tid = threadIdx.x;
  const int lane = tid & 63;
  const int wid = tid >> 6;
  const int wm = wid >> 2;
  const int wn = wid & 3;
  const int l15 = lane & 15;
  const int lq  = lane >> 4;
  const int srow = tid >> 3;
  const int scb  = (((tid & 7) ^ (srow & 7)) << 3);
  const int dcb  = (tid & 7) << 3;
  const int pb0 = ((lq ^ (l15 & 7)) << 3);
  const int pb1 = (((4 | lq) ^ (l15 & 7)) << 3);

  const ushort_t* gA = A + (long)(m0 + srow) * lda + scb;
  const ushort_t* gB = B + (long)(n0 + srow) * ldb + scb;

  floatx4 acc[8][4];
#pragma unroll
  for (int i = 0; i < 8; ++i)
#pragma unroll
    for (int j = 0; j < 4; ++j)
#pragma unroll
      for (int r = 0; r < 4; ++r) acc[i][j][r] = 0.0f;

  gemm_core(gA, gB, lda, ldb, K, As, Bs, srow, dcb, wm, wn, l15, pb0, pb1, acc);

#pragma unroll
  for (int mi = 0; mi < 8; ++mi) {
    const int mbase = m0 + wm*128 + (mi >> 2)*64 + (mi & 3)*16 + lq*4;
    float ss[4], ss2[4];
    if (STATS) {
#pragma unroll
      for (int r = 0; r < 4; ++r) { ss[r] = 0.0f; ss2[r] = 0.0f; }
    }
#pragma unroll
    for (int nj = 0; nj < 4; ++nj) {
      const int n = n0 + wn*64 + (nj >> 1)*32 + (nj & 1)*16 + l15;
      float v[4];
#pragma unroll
      for (int r = 0; r < 4; ++r) {
        v[r] = acc[mi][nj][r] * scale;
        if (BIASM == 1) v[r] += bias[mbase + r];
      }
      if (BIASM == 2) {
        const float bn_ = bias[n];
#pragma unroll
        for (int r = 0; r < 4; ++r) v[r] += bn_;
      }
      if (STATS) {
#pragma unroll
        for (int r = 0; r < 4; ++r) { ss[r] += v[r]; ss2[r] += v[r] * v[r]; }
      }
      if (POOLM == 0) {
#pragma unroll
        for (int r = 0; r < 4; ++r) {
          if (OUTF32) Cf[(long)(mbase + r) * ldc + n] = v[r];
          else        Cb[(long)(mbase + r) * ldc + n] = f2bf(v[r]);
        }
      } else if (POOLM == 1) {
#pragma unroll
        for (int r = 0; r < 4; ++r) {
          float o = __shfl_xor(v[r], 1);
          float w = fmaxf(v[r], o);
          if ((lane & 1) == 0) {
            if (OUTF32) Cf[(long)(mbase + r) * ldc + (n >> 1)] = w;
            else        Cb[(long)(mbase + r) * ldc + (n >> 1)] = f2bf(w);
          }
        }
      } else {
        float w0 = fmaxf(v[0], v[1]);
        float w1 = fmaxf(v[2], v[3]);
        const int mh = mbase >> 1;
        if (OUTF32) {
          Cf[(long)mh * ldc + n] = w0;
          Cf[(long)(mh + 1) * ldc + n] = w1;
        } else {
          Cb[(long)mh * ldc + n] = f2bf(w0);
          Cb[(long)(mh + 1) * ldc + n] = f2bf(w1);
        }
      }
    }
    if (STATS) {
#pragma unroll
      for (int o = 1; o < 16; o <<= 1) {
#pragma unroll
        for (int r = 0; r < 4; ++r) {
          ss[r]  += __shfl_xor(ss[r],  o);
          ss2[r] += __shfl_xor(ss2[r], o);
        }
      }
      if (l15 == 0) {
        const int chb = wm*128 + (mi >> 2)*64 + (mi & 3)*16 + lq*4;
#pragma unroll
        for (int r = 0; r < 4; ++r) part[wn][chb + r] = make_float2(ss[r], ss2[r]);
      }
    }
  }
  if (STATS) {
    __syncthreads();
    if (tid < 256) {
      float2 p0 = part[0][tid], p1 = part[1][tid], p2 = part[2][tid], p3 = part[3][tid];
      float2 p = make_float2(p0.x + p1.x + p2.x + p3.x, p0.y + p1.y + p2.y + p3.y);
      pstat[((long)blockIdx.z * gridDim.x + blockIdx.x) * 1024 + m0 + tid] = p;
    }
  }
}

// ============================================================================
// Fused Q + KV projection (256^2 8-phase), K=1024, 48 tiles/z = 768 blocks.
// ============================================================================
__global__ __launch_bounds__(512, 2)
void gemm_qkv(const ushort_t* __restrict__ xT, const ushort_t* __restrict__ Wq_b,
              ushort_t* __restrict__ Qt, ushort_t* __restrict__ KV,
              const float* __restrict__ bq, const float* __restrict__ bkv)
{
  __shared__ ushort_t As[2][256][64];
  __shared__ ushort_t Bs[2][256][64];

  const int z = blockIdx.z;
  const int id = blockIdx.x;
  const bool isQ = id < 16;
  const int bx = isQ ? (id & 1) : ((id - 16) & 7);
  const int by = isQ ? (id >> 1) : ((id - 16) >> 3);
  const int m0 = by * 256;
  const int n0 = bx * 256;
  const ushort_t* xz = xT + (long)z * 2048 * 1024;
  const ushort_t* Abase = isQ ? xz : (Wq_b + 512 * 1024);  // Wkv rows follow Wq
  const ushort_t* Bbase = isQ ? Wq_b : xz;

  const int tid = threadIdx.x;
  const int lane = tid & 63;
  const int wid = tid >> 6;
  const int wm = wid >> 2;
  const int wn = wid & 3;
  const int l15 = lane & 15;
  const int lq  = lane >> 4;
  const int srow = tid >> 3;
  const int scb  = (((tid & 7) ^ (srow & 7)) << 3);
  const int dcb  = (tid & 7) << 3;
  const int pb0 = ((lq ^ (l15 & 7)) << 3);
  const int pb1 = (((4 | lq) ^ (l15 & 7)) << 3);

  const ushort_t* gA = Abase + (long)(m0 + srow) * 1024 + scb;
  const ushort_t* gB = Bbase + (long)(n0 + srow) * 1024 + scb;

  floatx4 acc[8][4];
#pragma unroll
  for (int i = 0; i < 8; ++i)
#pragma unroll
    for (int j = 0; j < 4; ++j)
#pragma unroll
      for (int r = 0; r < 4; ++r) acc[i][j][r] = 0.0f;

  gemm_core(gA, gB, 1024, 1024, 1024, As, Bs, srow, dcb, wm, wn, l15, pb0, pb1, acc);

  if (isQ) {
    ushort_t* Cq = Qt + (long)z * 2048 * 512;
#pragma unroll
    for (int mi = 0; mi < 8; ++mi) {
      const int mbase = m0 + wm*128 + (mi >> 2)*64 + (mi & 3)*16 + lq*4;
#pragma unroll
      for (int nj = 0; nj < 4; ++nj) {
        const int n = n0 + wn*64 + (nj >> 1)*32 + (nj & 1)*16 + l15;
        const float bn_ = bq[n];
#pragma unroll
        for (int r = 0; r < 4; ++r)
          Cq[(long)(mbase + r) * 512 + n] = f2bf(acc[mi][nj][r] + bn_);
      }
    }
  } else {
    ushort_t* Ckv = KV + (long)z * 1024 * 1024;
#pragma unroll
    for (int mi = 0; mi < 8; ++mi) {
      const int mbase = m0 + wm*128 + (mi >> 2)*64 + (mi & 3)*16 + lq*4;
#pragma unroll
      for (int nj = 0; nj < 4; ++nj) {
        const int n = n0 + wn*64 + (nj >> 1)*32 + (nj & 1)*16 + l15;
#pragma unroll
        for (int r = 0; r < 4; ++r) {
          float v = acc[mi][nj][r] + bkv[mbase + r];
          float o = __shfl_xor(v, 1);
          float w = fmaxf(v, o);
          if ((lane & 1) == 0)
            Ckv[(long)(mbase + r) * 1024 + (n >> 1)] = f2bf(w);
        }
      }
    }
  }
}

// ============================================================================
// 128x128 GEMM (m97 structure) for small grids (WtT, Wco only).
// ============================================================================
template<int BIASM, int POOLM, bool OUTF32>
__global__ __launch_bounds__(256)
void gemm_bt(const ushort_t* __restrict__ A, long aStr,
             const ushort_t* __restrict__ B, long bStr,
             void* __restrict__ Cp, long cStr,
             int K, int lda, int ldb, int ldc,
             const float* __restrict__ bias, float scale)
{
  __shared__ ushort_t As[BM][BKK];
  __shared__ ushort_t Bs[BN][BKK];
  A += (long)blockIdx.z * aStr;
  B += (long)blockIdx.z * bStr;
  float* Cf = (float*)Cp + (OUTF32 ? (long)blockIdx.z * cStr : 0);
  ushort_t* Cb = (ushort_t*)Cp + (OUTF32 ? 0 : (long)blockIdx.z * cStr);
  const int m0 = blockIdx.y * BM;
  const int n0 = blockIdx.x * BN;
  const int tid = threadIdx.x;
  const int lane = tid & 63;
  const int wm = (tid >> 7) & 1;
  const int wn = (tid >> 6) & 1;
  const int ar = tid >> 3;
  const int ac = (tid & 7) * 8;

  floatx4 acc[4][4];
#pragma unroll
  for (int i = 0; i < 4; ++i)
#pragma unroll
    for (int j = 0; j < 4; ++j)
#pragma unroll
      for (int r = 0; r < 4; ++r) acc[i][j][r] = 0.0f;

  const int q8 = (lane >> 4) * 8;
  const int l15 = lane & 15;

  const ushort_t* gA = &A[(long)(m0 + ar) * lda + ac];
  const ushort_t* gB = &B[(long)(n0 + ar) * ldb + ac];
  const long aRow32 = (long)32 * lda;
  const long bRow32 = (long)32 * ldb;

  for (int k0 = 0; k0 < K; k0 += BKK) {
#pragma unroll
    for (int p = 0; p < 4; ++p)
      async16(gA + p * aRow32 + k0, &As[p * 32 + ar][ac]);
#pragma unroll
    for (int p = 0; p < 4; ++p)
      async16(gB + p * bRow32 + k0, &Bs[p * 32 + ar][ac]);
    __syncthreads();
#pragma unroll
    for (int kk = 0; kk < 2; ++kk) {
      const int kr = kk * 32 + q8;
      bf16x8 af[4], bfr[4];
#pragma unroll
      for (int i = 0; i < 4; ++i) {
        af[i]  = *(const bf16x8*)(&As[wm * 64 + i * 16 + l15][kr]);
        bfr[i] = *(const bf16x8*)(&Bs[wn * 64 + i * 16 + l15][kr]);
      }
#pragma unroll
      for (int i = 0; i < 4; ++i)
#pragma unroll
        for (int j = 0; j < 4; ++j)
          acc[i][j] = __builtin_amdgcn_mfma_f32_16x16x32_bf16(af[i], bfr[j], acc[i][j], 0, 0, 0);
    }
    __syncthreads();
  }

#pragma unroll
  for (int i = 0; i < 4; ++i) {
    const int mbase = m0 + wm * 64 + i * 16 + (lane >> 4) * 4;
#pragma unroll
    for (int j = 0; j < 4; ++j) {
      const int n = n0 + wn * 64 + j * 16 + l15;
      float v[4];
#pragma unroll
      for (int r = 0; r < 4; ++r) {
        v[r] = acc[i][j][r] * scale;
        if (BIASM == 1) v[r] += bias[mbase + r];
      }
      if (BIASM == 2) {
        const float bn_ = bias[n];
#pragma unroll
        for (int r = 0; r < 4; ++r) v[r] += bn_;
      }
      if (POOLM == 0) {
#pragma unroll
        for (int r = 0; r < 4; ++r) {
          if (OUTF32) Cf[(long)(mbase + r) * ldc + n] = v[r];
          else        Cb[(long)(mbase + r) * ldc + n] = f2bf(v[r]);
        }
      } else if (POOLM == 1) {
#pragma unroll
        for (int r = 0; r < 4; ++r) {
          float o = __shfl_xor(v[r], 1);
          float w = fmaxf(v[r], o);
          if ((lane & 1) == 0) {
            if (OUTF32) Cf[(long)(mbase + r) * ldc + (n >> 1)] = w;
            else        Cb[(long)(mbase + r) * ldc + (n >> 1)] = f2bf(w);
          }
        }
      } else {
        float w0 = fmaxf(v[0], v[1]);
        float w1 = fmaxf(v[2], v[3]);
        const int mh = mbase >> 1;
        if (OUTF32) {
          Cf[(long)mh * ldc + n] = w0;
          Cf[(long)(mh + 1) * ldc + n] = w1;
        } else {
          Cb[(long)mh * ldc + n] = f2bf(w0);
          Cb[(long)(mh + 1) * ldc + n] = f2bf(w1);
        }
      }
    }
  }
}

// ============================================================================
// Prologue union kernel: grid (32, 17, 16).
//  by < 16 : xT[t][c] = bf16(x[c][t]) transpose, 64x64 tiles (float4 reads,
//            ushort8 writes).
//  by == 16: weight fp32->bf16 convert (512 blocks x 256 thr x 16 elems) +
//            bkv concat (block cid==0).
// ============================================================================
__global__ __launch_bounds__(256)
void prolog(const float* __restrict__ x, ushort_t* __restrict__ xT,
            const float* __restrict__ Wq, const float* __restrict__ Wk,
            const float* __restrict__ Wv, const float* __restrict__ Wo,
            ushort_t* __restrict__ Wb,
            const float* __restrict__ bk, const float* __restrict__ bv,
            float* __restrict__ bkv)
{
  if (blockIdx.y == 16) {
    const int cid = blockIdx.z * 32 + blockIdx.x;          // 0..511
    const long base = (long)cid * 4096 + threadIdx.x * 16; // 16 elems/thread
    const float* srcs[4] = {Wq, Wk, Wv, Wo};
    const float* s = srcs[base >> 19];                     // 524288 elems each
    const long off = base & 524287;
#pragma unroll
    for (int p = 0; p < 4; ++p) {
      floatx4 v = *(const floatx4*)&s[off + p * 4];
      ushortx4 o;
#pragma unroll
      for (int r = 0; r < 4; ++r) o[r] = f2bf(v[r]);
      *(ushortx4*)&Wb[base + p * 4] = o;
    }
    if (cid == 0) {
      for (int j = threadIdx.x; j < 1024; j += 256)
        bkv[j] = (j < 512) ? bk[j] : bv[j - 512];
    }
    return;
  }
  __shared__ ushort_t tileT[64][72];
  const long boff = (long)blockIdx.z * 1024 * 2048;
  const int t0 = blockIdx.x * 64;
  const int r0 = blockIdx.y * 64;
  const int tx = threadIdx.x & 15;
  const int ty = threadIdx.x >> 4;
#pragma unroll
  for (int i = 0; i < 4; ++i) {
    const int c = ty + 16 * i;
    floatx4 v = *(const floatx4*)&x[boff + (long)(r0 + c) * 2048 + t0 + 4 * tx];
#pragma unroll
    for (int j = 0; j < 4; ++j) tileT[4 * tx + j][c] = f2bf(v[j]);
  }
  __syncthreads();
  const int cx = threadIdx.x & 7;
  const int tw = threadIdx.x >> 3;
#pragma unroll
  for (int i = 0; i < 2; ++i) {
    const int t = tw + 32 * i;
    ushortx8 w = *(const ushortx8*)&tileT[t][8 * cx];
    *(ushortx8*)&xT[boff + (long)(t0 + t) * 1024 + r0 + 8 * cx] = w;
  }
}

// out = gamma*(yb-mean)*rstd + beta + x ; yb is bf16 pre-BN y. One block per
// (b,c) row; per-block reduce of 128 L2-hot pstat partials, then apply.
__global__ __launch_bounds__(256)
void bn_apply(const ushort_t* __restrict__ yb, const float* __restrict__ x,
              float* __restrict__ out, const float2* __restrict__ pstat,
              const float* __restrict__ gamma, const float* __restrict__ beta)
{
  const int bc = blockIdx.x;
  const int c = bc & 1023;
  float s = 0.0f, s2 = 0.0f;
  if (threadIdx.x < 128) {
    float2 p = pstat[(long)threadIdx.x * 1024 + c];
    s = p.x; s2 = p.y;
  }
#pragma unroll
  for (int o = 32; o > 0; o >>= 1) { s += __shfl_down(s, o); s2 += __shfl_down(s2, o); }
  __shared__ float red[4];
  __shared__ float smv[2];
  const int w = threadIdx.x >> 6;
  if ((threadIdx.x & 63) == 0 && w < 2) { red[w] = s; red[2 + w] = s2; }
  __syncthreads();
  if (threadIdx.x == 0) {
    float ts = red[0] + red[1], ts2 = red[2] + red[3];
    const float inv = 1.0f / (16.0f * 2048.0f);
    float mean = ts * inv;
    float var = ts2 * inv - mean * mean;
    smv[0] = mean;
    smv[1] = rsqrtf(var + 1e-5f);
  }
  __syncthreads();
  const float mean = smv[0];
  const float g = gamma[c] * smv[1];
  const float bt = beta[c];
  const long off = (long)bc * 2048;
  const ushortx8* yp = (const ushortx8*)(yb + off);
  const floatx4* xp = (const floatx4*)(x + off);
  floatx4* op = (floatx4*)(out + off);
  const int t = threadIdx.x;           // 256 threads x 8 elems = 2048
  ushortx8 v8 = yp[t];
  floatx4 x0 = xp[2 * t], x1 = xp[2 * t + 1];
  floatx4 o0, o1;
#pragma unroll
  for (int r = 0; r < 4; ++r) o0[r] = (bf2f(v8[r]) - mean) * g + bt + x0[r];
#pragma unroll
  for (int r = 0; r < 4; ++r) o1[r] = (bf2f(v8[4 + r]) - mean) * g + bt + x1[r];
  op[2 * t] = o0;
  op[2 * t + 1] = o1;
}

extern "C" void kernel_launch(void* const* d_in, const int* in_sizes, int n_in,
                              void* d_out, int out_size, void* d_ws, size_t ws_size,
                              hipStream_t stream) {
  (void)in_sizes; (void)n_in; (void)out_size; (void)ws_size;
  const float* x  = (const float*)d_in[0];
  const float* Wq = (const float*)d_in[1];
  const float* bq = (const float*)d_in[2];
  const float* Wk = (const float*)d_in[3];
  const float* bk = (const float*)d_in[4];
  const float* Wv = (const float*)d_in[5];
  const float* bv = (const float*)d_in[6];
  const float* Wo = (const float*)d_in[7];
  const float* bo = (const float*)d_in[8];
  const float* gamma = (const float*)d_in[9];
  const float* beta  = (const float*)d_in[10];
  float* out = (float*)d_out;

  const int Cc = 1024, T = 2048, D = 512, S = 1024;

  // Chain (R4 structure + prolog union):
  // prolog (transpose+convert) -> qkv (fused 256^2 8ph) -> WtT = Kd V^T ->
  // Wco = Wo WtT^T/T -> yb = bf16(Wco Qt^T + bo) with fused BN partials
  // (256^2 8ph) -> bn_apply.
  ushort_t* ws   = (ushort_t*)d_ws;
  ushort_t* xT   = ws;                  // (B,T,C)  33,554,432
  ushort_t* Qt   = ws + 33554432;       // (B,T,D)  16,777,216
  ushort_t* KV   = ws + 50331648;       // (B,2D,S) 16,777,216
  ushort_t* WtT  = ws + 67108864;       // (B,D,D)   4,194,304
  ushort_t* Wco  = ws + 71303168;       // (B,C,D)   8,388,608
  ushort_t* yb   = ws + 79691776;       // (B,C,T)  33,554,432 bf16 pre-BN y
  ushort_t* Wq_b = ws + 113246208;      //  2,097,152 (Wq,Wk,Wv,Wo contiguous)
  ushort_t* Wo_b = ws + 113246208 + 3 * 524288;
  float*    bkv  = (float*)(ws + 115343360);    // 1024 floats
  float2*   pstat = (float2*)(ws + 115345408);  // 128*1024 float2 = 1 MB

  dim3 blk(256);
  dim3 blk512(512);

  // 0. Prologue: xT = bf16(x^T) (by<16) + weights->bf16 + bkv concat (by==16).
  prolog<<<dim3(32, 17, 16), blk, 0, stream>>>(x, xT, Wq, Wk, Wv, Wo, Wq_b,
                                               bk, bv, bkv);

  // 1. Fused Q + KV projection (768 blocks = 3 clean rounds).
  gemm_qkv<<<dim3(48, 1, 16), blk512, 0, stream>>>(xT, Wq_b, Qt, KV, bq, bkv);

  // 2. WtT (D,D) = Kd x V^T : K=S.
  gemm_bt<0, 0, false><<<dim3(D / 128, D / 128, 16), blk, 0, stream>>>(
      KV, (long)2 * D * S, KV + (long)D * S, (long)2 * D * S, WtT, (long)D * D,
      S, S, S, D, nullptr, 1.0f);
  // 3. Wco (C,D) = Wo x WtT^T / T : K=D.
  gemm_bt<0, 0, false><<<dim3(D / 128, Cc / 128, 16), blk, 0, stream>>>(
      Wo_b, 0, WtT, (long)D * D, Wco, (long)Cc * D,
      D, D, D, D, nullptr, 1.0f / 2048.0f);

  // 4. yb = bf16(Wco x Qt^T + bo), (B,C,T); fused BN partials (256^2 8-phase;
  //    R5 showed 128^2 is ~20us slower here).
  gemm256<1, 0, false, true><<<dim3(T / 256, Cc / 256, 16), blk512, 0, stream>>>(
      Wco, (long)Cc * D, Qt, (long)T * D, yb, (long)Cc * T,
      D, D, D, T, bo, 1.0f, pstat);

  // 5. BN finalize (folded) + apply + residual -> fp32 out.
  bn_apply<<<dim3(16384), blk, 0, stream>>>(yb, x, out, pstat, gamma, beta);
}

// Round 8
// 509.785 us; speedup vs baseline: 1.0463x; 1.0007x over previous
//
#include <hip/hip_runtime.h>

typedef unsigned short ushort_t;
typedef __bf16 bf16x8 __attribute__((ext_vector_type(8)));
typedef float floatx4 __attribute__((ext_vector_type(4)));
typedef ushort_t ushortx8 __attribute__((ext_vector_type(8)));
typedef ushort_t ushortx4 __attribute__((ext_vector_type(4)));

#define BM 128
#define BN 128
#define BKK 64

__device__ __forceinline__ ushort_t f2bf(float f) {
  union { float f; unsigned int u; } c; c.f = f;
  unsigned int r = c.u + 0x7FFFu + ((c.u >> 16) & 1u);
  return (ushort_t)(r >> 16);
}

__device__ __forceinline__ float bf2f(ushort_t u) {
  union { unsigned int u; float f; } c; c.u = ((unsigned int)u) << 16;
  return c.f;
}

// Async 16B global->LDS (lane-contiguous LDS dest required: base + lane*16).
__device__ __forceinline__ void async16(const ushort_t* g, ushort_t* l) {
  __builtin_amdgcn_global_load_lds(
      (const __attribute__((address_space(1))) unsigned int*)g,
      (__attribute__((address_space(3))) unsigned int*)l, 16, 0, 0);
}

// ============================================================================
// Shared 256x256 8-phase K-loop core (m201 template: T2 LDS swizzle + T3/T4
// counted vmcnt + T5 setprio). 812 TF measured at K=1024 == 96% of the known
// plain-HIP ceiling for this regime (m248: 848 TF) -- do not touch.
// NOTE (R5 lesson): at K=512 this still beats the 128^2 m97 structure
// (~65-70us vs ~90us for the y-GEMM) -- do not retile small-K GEMMs to 128^2
// when the grid already fills the machine.
// ============================================================================
__device__ __forceinline__ void gemm_core(
    const ushort_t* __restrict__ gA, const ushort_t* __restrict__ gB,
    int lda, int ldb, int K,
    ushort_t (&As)[2][256][64], ushort_t (&Bs)[2][256][64],
    const int srow, const int dcb, const int wm, const int wn,
    const int l15, const int pb0, const int pb1,
    floatx4 (&acc)[8][4])
{
  bf16x8 aA[4][2], bB0[2][2], bB1[2][2];
  const int NT = K >> 6;   // K-tiles of 64
  const int NI = NT >> 1;  // iterations (2 tiles each)

#define STAGE_A(sl, hf, kt) do { \
    const ushort_t* _s = gA + (long)((hf) * 128) * lda + ((kt) << 6); \
    async16(_s,                  &As[sl][(hf)*128      + srow][dcb]); \
    async16(_s + (long)64 * lda, &As[sl][(hf)*128 + 64 + srow][dcb]); \
  } while (0)
#define STAGE_B(sl, hf, kt) do { \
    const ushort_t* _s = gB + (long)((hf) * 128) * ldb + ((kt) << 6); \
    async16(_s,                  &Bs[sl][(hf)*128      + srow][dcb]); \
    async16(_s + (long)64 * ldb, &Bs[sl][(hf)*128 + 64 + srow][dcb]); \
  } while (0)
#define LD_A(sl, mh) do { \
    _Pragma("unroll") for (int _i = 0; _i < 4; ++_i) { \
      const int _r = wm*128 + (mh)*64 + _i*16 + l15; \
      aA[_i][0] = *(const bf16x8*)&As[sl][_r][pb0]; \
      aA[_i][1] = *(const bf16x8*)&As[sl][_r][pb1]; } \
  } while (0)
#define LD_B(sl, nh, dst) do { \
    _Pragma("unroll") for (int _j = 0; _j < 2; ++_j) { \
      const int _r = wn*64 + (nh)*32 + _j*16 + l15; \
      dst[_j][0] = *(const bf16x8*)&Bs[sl][_r][pb0]; \
      dst[_j][1] = *(const bf16x8*)&Bs[sl][_r][pb1]; } \
  } while (0)
#define MMA(mh, nh, bfr) do { \
    __builtin_amdgcn_s_setprio(1); \
    _Pragma("unroll") for (int _i = 0; _i < 4; ++_i) \
    _Pragma("unroll") for (int _j = 0; _j < 2; ++_j) { \
      floatx4& _c = acc[(mh)*4 + _i][(nh)*2 + _j]; \
      _c = __builtin_amdgcn_mfma_f32_16x16x32_bf16(aA[_i][0], (bfr)[_j][0], _c, 0, 0, 0); \
      _c = __builtin_amdgcn_mfma_f32_16x16x32_bf16(aA[_i][1], (bfr)[_j][1], _c, 0, 0, 0); } \
    __builtin_amdgcn_s_setprio(0); \
  } while (0)
#define SBAR  __builtin_amdgcn_s_barrier()
#define LGKM0 asm volatile("s_waitcnt lgkmcnt(0)" ::: "memory")
#define VM4   asm volatile("s_waitcnt vmcnt(4)" ::: "memory")
#define VM0   asm volatile("s_waitcnt vmcnt(0)" ::: "memory")

  // Prologue: tile0 (4 halves) + A0(1), B1(1).
  STAGE_A(0, 0, 0); STAGE_A(0, 1, 0); STAGE_B(0, 0, 0); STAGE_B(0, 1, 0);
  STAGE_A(1, 0, 1); STAGE_B(1, 1, 1);
  VM4; SBAR;

  for (int i = 0; i < NI - 1; ++i) {
    const int t1 = 2*i + 1, t2 = 2*i + 2, t3 = 2*i + 3;
    LD_A(0, 0); LD_B(0, 0, bB0); STAGE_A(1, 1, t1);
    SBAR; LGKM0; MMA(0, 0, bB0); SBAR;
    LD_B(0, 1, bB1); STAGE_B(1, 0, t1);
    SBAR; LGKM0; MMA(0, 1, bB1); SBAR;
    LD_A(0, 1); STAGE_A(0, 0, t2);
    SBAR; LGKM0; MMA(1, 1, bB1); SBAR;
    STAGE_B(0, 1, t2);
    SBAR; LGKM0; MMA(1, 0, bB0); VM4; SBAR;
    LD_A(1, 0); LD_B(1, 0, bB0); STAGE_A(0, 1, t2);
    SBAR; LGKM0; MMA(0, 0, bB0); SBAR;
    LD_B(1, 1, bB1); STAGE_B(0, 0, t2);
    SBAR; LGKM0; MMA(0, 1, bB1); SBAR;
    LD_A(1, 1); STAGE_A(1, 0, t3);
    SBAR; LGKM0; MMA(1, 1, bB1); SBAR;
    STAGE_B(1, 1, t3);
    SBAR; LGKM0; MMA(1, 0, bB0); VM4; SBAR;
  }
  // Peeled final iteration.
  {
    const int t1 = NT - 1;
    LD_A(0, 0); LD_B(0, 0, bB0); STAGE_A(1, 1, t1);
    SBAR; LGKM0; MMA(0, 0, bB0); SBAR;
    LD_B(0, 1, bB1); STAGE_B(1, 0, t1);
    SBAR; LGKM0; MMA(0, 1, bB1); SBAR;
    LD_A(0, 1);
    SBAR; LGKM0; MMA(1, 1, bB1); SBAR;
    SBAR; LGKM0; MMA(1, 0, bB0); VM0; SBAR;
    LD_A(1, 0); LD_B(1, 0, bB0);
    SBAR; LGKM0; MMA(0, 0, bB0); SBAR;
    LD_B(1, 1, bB1);
    SBAR; LGKM0; MMA(0, 1, bB1); SBAR;
    LD_A(1, 1);
    SBAR; LGKM0; MMA(1, 1, bB1); SBAR;
    LGKM0; MMA(1, 0, bB0);
  }
#undef STAGE_A
#undef STAGE_B
#undef LD_A
#undef LD_B
#undef MMA
#undef SBAR
#undef LGKM0
#undef VM4
#undef VM0
}

// ============================================================================
// Generic 256^2 GEMM wrapper. BIASM: 0 none, 1 bias[m], 2 bias[n].
// POOLM: 0 none, 1 pool n-pairs, 2 pool m-pairs. OUTF32: write float.
// STATS: per-channel(m) sum/sumsq partials -> pstat (float2).
// ============================================================================
template<int BIASM, int POOLM, bool OUTF32, bool STATS = false>
__global__ __launch_bounds__(512, 2)
void gemm256(const ushort_t* __restrict__ A, long aStr,
             const ushort_t* __restrict__ B, long bStr,
             void* __restrict__ Cp, long cStr,
             int K, int lda, int ldb, int ldc,
             const float* __restrict__ bias, float scale,
             float2* __restrict__ pstat = nullptr)
{
  __shared__ ushort_t As[2][256][64];
  __shared__ ushort_t Bs[2][256][64];
  __shared__ float2 part[4][256];

  A += (long)blockIdx.z * aStr;
  B += (long)blockIdx.z * bStr;
  float* Cf = (float*)Cp + (OUTF32 ? (long)blockIdx.z * cStr : 0);
  ushort_t* Cb = (ushort_t*)Cp + (OUTF32 ? 0 : (long)blockIdx.z * cStr);
  const int m0 = blockIdx.y * 256;
  const int n0 = blockIdx.x * 256;
  const int tid = threadIdx.x;
  const int lane = tid & 63;
  const int wid = tid >> 6;
  const int wm = wid >> 2;
  const int wn = wid & 3;
  const int l15 = lane & 15;
  const int lq  = lane >> 4;
  const int srow = tid >> 3;
  const int scb  = (((tid & 7) ^ (srow & 7)) << 3);
  const int dcb  = (tid & 7) << 3;
  const int pb0 = ((lq ^ (l15 & 7)) << 3);
  const int pb1 = (((4 | lq) ^ (l15 & 7)) << 3);

  const ushort_t* gA = A + (long)(m0 + srow) * lda + scb;
  const ushort_t* gB = B + (long)(n0 + srow) * ldb + scb;

  floatx4 acc[8][4];
#pragma unroll
  for (int i = 0; i < 8; ++i)
#pragma unroll
    for (int j = 0; j < 4; ++j)
#pragma unroll
      for (int r = 0; r < 4; ++r) acc[i][j][r] = 0.0f;

  gemm_core(gA, gB, lda, ldb, K, As, Bs, srow, dcb, wm, wn, l15, pb0, pb1, acc);

#pragma unroll
  for (int mi = 0; mi < 8; ++mi) {
    const int mbase = m0 + wm*128 + (mi >> 2)*64 + (mi & 3)*16 + lq*4;
    float ss[4], ss2[4];
    if (STATS) {
#pragma unroll
      for (int r = 0; r < 4; ++r) { ss[r] = 0.0f; ss2[r] = 0.0f; }
    }
#pragma unroll
    for (int nj = 0; nj < 4; ++nj) {
      const int n = n0 + wn*64 + (nj >> 1)*32 + (nj & 1)*16 + l15;
      float v[4];
#pragma unroll
      for (int r = 0; r < 4; ++r) {
        v[r] = acc[mi][nj][r] * scale;
        if (BIASM == 1) v[r] += bias[mbase + r];
      }
      if (BIASM == 2) {
        const float bn_ = bias[n];
#pragma unroll
        for (int r = 0; r < 4; ++r) v[r] += bn_;
      }
      if (STATS) {
#pragma unroll
        for (int r = 0; r < 4; ++r) { ss[r] += v[r]; ss2[r] += v[r] * v[r]; }
      }
      if (POOLM == 0) {
#pragma unroll
        for (int r = 0; r < 4; ++r) {
          if (OUTF32) Cf[(long)(mbase + r) * ldc + n] = v[r];
          else        Cb[(long)(mbase + r) * ldc + n] = f2bf(v[r]);
        }
      } else if (POOLM == 1) {
#pragma unroll
        for (int r = 0; r < 4; ++r) {
          float o = __shfl_xor(v[r], 1);
          float w = fmaxf(v[r], o);
          if ((lane & 1) == 0) {
            if (OUTF32) Cf[(long)(mbase + r) * ldc + (n >> 1)] = w;
            else        Cb[(long)(mbase + r) * ldc + (n >> 1)] = f2bf(w);
          }
        }
      } else {
        float w0 = fmaxf(v[0], v[1]);
        float w1 = fmaxf(v[2], v[3]);
        const int mh = mbase >> 1;
        if (OUTF32) {
          Cf[(long)mh * ldc + n] = w0;
          Cf[(long)(mh + 1) * ldc + n] = w1;
        } else {
          Cb[(long)mh * ldc + n] = f2bf(w0);
          Cb[(long)(mh + 1) * ldc + n] = f2bf(w1);
        }
      }
    }
    if (STATS) {
#pragma unroll
      for (int o = 1; o < 16; o <<= 1) {
#pragma unroll
        for (int r = 0; r < 4; ++r) {
          ss[r]  += __shfl_xor(ss[r],  o);
          ss2[r] += __shfl_xor(ss2[r], o);
        }
      }
      if (l15 == 0) {
        const int chb = wm*128 + (mi >> 2)*64 + (mi & 3)*16 + lq*4;
#pragma unroll
        for (int r = 0; r < 4; ++r) part[wn][chb + r] = make_float2(ss[r], ss2[r]);
      }
    }
  }
  if (STATS) {
    __syncthreads();
    if (tid < 256) {
      float2 p0 = part[0][tid], p1 = part[1][tid], p2 = part[2][tid], p3 = part[3][tid];
      float2 p = make_float2(p0.x + p1.x + p2.x + p3.x, p0.y + p1.y + p2.y + p3.y);
      pstat[((long)blockIdx.z * gridDim.x + blockIdx.x) * 1024 + m0 + tid] = p;
    }
  }
}

// ============================================================================
// Fused Q + KV projection (256^2 8-phase), K=1024, 48 tiles/z = 768 blocks.
// ============================================================================
__global__ __launch_bounds__(512, 2)
void gemm_qkv(const ushort_t* __restrict__ xT, const ushort_t* __restrict__ Wq_b,
              ushort_t* __restrict__ Qt, ushort_t* __restrict__ KV,
              const float* __restrict__ bq, const float* __restrict__ bkv)
{
  __shared__ ushort_t As[2][256][64];
  __shared__ ushort_t Bs[2][256][64];

  const int z = blockIdx.z;
  const int id = blockIdx.x;
  const bool isQ = id < 16;
  const int bx = isQ ? (id & 1) : ((id - 16) & 7);
  const int by = isQ ? (id >> 1) : ((id - 16) >> 3);
  const int m0 = by * 256;
  const int n0 = bx * 256;
  const ushort_t* xz = xT + (long)z * 2048 * 1024;
  const ushort_t* Abase = isQ ? xz : (Wq_b + 512 * 1024);  // Wkv rows follow Wq
  const ushort_t* Bbase = isQ ? Wq_b : xz;

  const int tid = threadIdx.x;
  const int lane = tid & 63;
  const int wid = tid >> 6;
  const int wm = wid >> 2;
  const int wn = wid & 3;
  const int l15 = lane & 15;
  const int lq  = lane >> 4;
  const int srow = tid >> 3;
  const int scb  = (((tid & 7) ^ (srow & 7)) << 3);
  const int dcb  = (tid & 7) << 3;
  const int pb0 = ((lq ^ (l15 & 7)) << 3);
  const int pb1 = (((4 | lq) ^ (l15 & 7)) << 3);

  const ushort_t* gA = Abase + (long)(m0 + srow) * 1024 + scb;
  const ushort_t* gB = Bbase + (long)(n0 + srow) * 1024 + scb;

  floatx4 acc[8][4];
#pragma unroll
  for (int i = 0; i < 8; ++i)
#pragma unroll
    for (int j = 0; j < 4; ++j)
#pragma unroll
      for (int r = 0; r < 4; ++r) acc[i][j][r] = 0.0f;

  gemm_core(gA, gB, 1024, 1024, 1024, As, Bs, srow, dcb, wm, wn, l15, pb0, pb1, acc);

  if (isQ) {
    ushort_t* Cq = Qt + (long)z * 2048 * 512;
#pragma unroll
    for (int mi = 0; mi < 8; ++mi) {
      const int mbase = m0 + wm*128 + (mi >> 2)*64 + (mi & 3)*16 + lq*4;
#pragma unroll
      for (int nj = 0; nj < 4; ++nj) {
        const int n = n0 + wn*64 + (nj >> 1)*32 + (nj & 1)*16 + l15;
        const float bn_ = bq[n];
#pragma unroll
        for (int r = 0; r < 4; ++r)
          Cq[(long)(mbase + r) * 512 + n] = f2bf(acc[mi][nj][r] + bn_);
      }
    }
  } else {
    ushort_t* Ckv = KV + (long)z * 1024 * 1024;
#pragma unroll
    for (int mi = 0; mi < 8; ++mi) {
      const int mbase = m0 + wm*128 + (mi >> 2)*64 + (mi & 3)*16 + lq*4;
#pragma unroll
      for (int nj = 0; nj < 4; ++nj) {
        const int n = n0 + wn*64 + (nj >> 1)*32 + (nj & 1)*16 + l15;
#pragma unroll
        for (int r = 0; r < 4; ++r) {
          float v = acc[mi][nj][r] + bkv[mbase + r];
          float o = __shfl_xor(v, 1);
          float w = fmaxf(v, o);
          if ((lane & 1) == 0)
            Ckv[(long)(mbase + r) * 1024 + (n >> 1)] = f2bf(w);
        }
      }
    }
  }
}

// ============================================================================
// 128x128 GEMM (m97 structure) for small grids (WtT, Wco only).
// ============================================================================
template<int BIASM, int POOLM, bool OUTF32>
__global__ __launch_bounds__(256)
void gemm_bt(const ushort_t* __restrict__ A, long aStr,
             const ushort_t* __restrict__ B, long bStr,
             void* __restrict__ Cp, long cStr,
             int K, int lda, int ldb, int ldc,
             const float* __restrict__ bias, float scale)
{
  __shared__ ushort_t As[BM][BKK];
  __shared__ ushort_t Bs[BN][BKK];
  A += (long)blockIdx.z * aStr;
  B += (long)blockIdx.z * bStr;
  float* Cf = (float*)Cp + (OUTF32 ? (long)blockIdx.z * cStr : 0);
  ushort_t* Cb = (ushort_t*)Cp + (OUTF32 ? 0 : (long)blockIdx.z * cStr);
  const int m0 = blockIdx.y * BM;
  const int n0 = blockIdx.x * BN;
  const int tid = threadIdx.x;
  const int lane = tid & 63;
  const int wm = (tid >> 7) & 1;
  const int wn = (tid >> 6) & 1;
  const int ar = tid >> 3;
  const int ac = (tid & 7) * 8;

  floatx4 acc[4][4];
#pragma unroll
  for (int i = 0; i < 4; ++i)
#pragma unroll
    for (int j = 0; j < 4; ++j)
#pragma unroll
      for (int r = 0; r < 4; ++r) acc[i][j][r] = 0.0f;

  const int q8 = (lane >> 4) * 8;
  const int l15 = lane & 15;

  const ushort_t* gA = &A[(long)(m0 + ar) * lda + ac];
  const ushort_t* gB = &B[(long)(n0 + ar) * ldb + ac];
  const long aRow32 = (long)32 * lda;
  const long bRow32 = (long)32 * ldb;

  for (int k0 = 0; k0 < K; k0 += BKK) {
#pragma unroll
    for (int p = 0; p < 4; ++p)
      async16(gA + p * aRow32 + k0, &As[p * 32 + ar][ac]);
#pragma unroll
    for (int p = 0; p < 4; ++p)
      async16(gB + p * bRow32 + k0, &Bs[p * 32 + ar][ac]);
    __syncthreads();
#pragma unroll
    for (int kk = 0; kk < 2; ++kk) {
      const int kr = kk * 32 + q8;
      bf16x8 af[4], bfr[4];
#pragma unroll
      for (int i = 0; i < 4; ++i) {
        af[i]  = *(const bf16x8*)(&As[wm * 64 + i * 16 + l15][kr]);
        bfr[i] = *(const bf16x8*)(&Bs[wn * 64 + i * 16 + l15][kr]);
      }
#pragma unroll
      for (int i = 0; i < 4; ++i)
#pragma unroll
        for (int j = 0; j < 4; ++j)
          acc[i][j] = __builtin_amdgcn_mfma_f32_16x16x32_bf16(af[i], bfr[j], acc[i][j], 0, 0, 0);
    }
    __syncthreads();
  }

#pragma unroll
  for (int i = 0; i < 4; ++i) {
    const int mbase = m0 + wm * 64 + i * 16 + (lane >> 4) * 4;
#pragma unroll
    for (int j = 0; j < 4; ++j) {
      const int n = n0 + wn * 64 + j * 16 + l15;
      float v[4];
#pragma unroll
      for (int r = 0; r < 4; ++r) {
        v[r] = acc[i][j][r] * scale;
        if (BIASM == 1) v[r] += bias[mbase + r];
      }
      if (BIASM == 2) {
        const float bn_ = bias[n];
#pragma unroll
        for (int r = 0; r < 4; ++r) v[r] += bn_;
      }
      if (POOLM == 0) {
#pragma unroll
        for (int r = 0; r < 4; ++r) {
          if (OUTF32) Cf[(long)(mbase + r) * ldc + n] = v[r];
          else        Cb[(long)(mbase + r) * ldc + n] = f2bf(v[r]);
        }
      } else if (POOLM == 1) {
#pragma unroll
        for (int r = 0; r < 4; ++r) {
          float o = __shfl_xor(v[r], 1);
          float w = fmaxf(v[r], o);
          if ((lane & 1) == 0) {
            if (OUTF32) Cf[(long)(mbase + r) * ldc + (n >> 1)] = w;
            else        Cb[(long)(mbase + r) * ldc + (n >> 1)] = f2bf(w);
          }
        }
      } else {
        float w0 = fmaxf(v[0], v[1]);
        float w1 = fmaxf(v[2], v[3]);
        const int mh = mbase >> 1;
        if (OUTF32) {
          Cf[(long)mh * ldc + n] = w0;
          Cf[(long)(mh + 1) * ldc + n] = w1;
        } else {
          Cb[(long)mh * ldc + n] = f2bf(w0);
          Cb[(long)(mh + 1) * ldc + n] = f2bf(w1);
        }
      }
    }
  }
}

// ============================================================================
// Prologue union kernel: grid (32, 17, 16).
//  by < 16 : xT[t][c] = bf16(x[c][t]) transpose, 64x64 tiles (float4 reads,
//            ushort8 writes).
//  by == 16: weight fp32->bf16 convert (512 blocks x 256 thr x 16 elems) +
//            bkv concat (block cid==0).
// ============================================================================
__global__ __launch_bounds__(256)
void prolog(const float* __restrict__ x, ushort_t* __restrict__ xT,
            const float* __restrict__ Wq, const float* __restrict__ Wk,
            const float* __restrict__ Wv, const float* __restrict__ Wo,
            ushort_t* __restrict__ Wb,
            const float* __restrict__ bk, const float* __restrict__ bv,
            float* __restrict__ bkv)
{
  if (blockIdx.y == 16) {
    const int cid = blockIdx.z * 32 + blockIdx.x;          // 0..511
    const long base = (long)cid * 4096 + threadIdx.x * 16; // 16 elems/thread
    const float* srcs[4] = {Wq, Wk, Wv, Wo};
    const float* s = srcs[base >> 19];                     // 524288 elems each
    const long off = base & 524287;
#pragma unroll
    for (int p = 0; p < 4; ++p) {
      floatx4 v = *(const floatx4*)&s[off + p * 4];
      ushortx4 o;
#pragma unroll
      for (int r = 0; r < 4; ++r) o[r] = f2bf(v[r]);
      *(ushortx4*)&Wb[base + p * 4] = o;
    }
    if (cid == 0) {
      for (int j = threadIdx.x; j < 1024; j += 256)
        bkv[j] = (j < 512) ? bk[j] : bv[j - 512];
    }
    return;
  }
  __shared__ ushort_t tileT[64][72];
  const long boff = (long)blockIdx.z * 1024 * 2048;
  const int t0 = blockIdx.x * 64;
  const int r0 = blockIdx.y * 64;
  const int tx = threadIdx.x & 15;
  const int ty = threadIdx.x >> 4;
#pragma unroll
  for (int i = 0; i < 4; ++i) {
    const int c = ty + 16 * i;
    floatx4 v = *(const floatx4*)&x[boff + (long)(r0 + c) * 2048 + t0 + 4 * tx];
#pragma unroll
    for (int j = 0; j < 4; ++j) tileT[4 * tx + j][c] = f2bf(v[j]);
  }
  __syncthreads();
  const int cx = threadIdx.x & 7;
  const int tw = threadIdx.x >> 3;
#pragma unroll
  for (int i = 0; i < 2; ++i) {
    const int t = tw + 32 * i;
    ushortx8 w = *(const ushortx8*)&tileT[t][8 * cx];
    *(ushortx8*)&xT[boff + (long)(t0 + t) * 1024 + r0 + 8 * cx] = w;
  }
}

// out = gamma*(yb-mean)*rstd + beta + x ; yb is bf16 pre-BN y.
// One block PER CHANNEL (grid 1024): reduce the 128 pstat partials once,
// then apply to all 16 batch rows (was: 16384 blocks each redundantly
// re-reducing the same 128 partials for its channel).
__global__ __launch_bounds__(256)
void bn_apply(const ushort_t* __restrict__ yb, const float* __restrict__ x,
              float* __restrict__ out, const float2* __restrict__ pstat,
              const float* __restrict__ gamma, const float* __restrict__ beta)
{
  const int c = blockIdx.x;   // 0..1023
  float s = 0.0f, s2 = 0.0f;
  if (threadIdx.x < 128) {
    float2 p = pstat[(long)threadIdx.x * 1024 + c];
    s = p.x; s2 = p.y;
  }
#pragma unroll
  for (int o = 32; o > 0; o >>= 1) { s += __shfl_down(s, o); s2 += __shfl_down(s2, o); }
  __shared__ float red[4];
  __shared__ float smv[2];
  const int w = threadIdx.x >> 6;
  if ((threadIdx.x & 63) == 0 && w < 2) { red[w] = s; red[2 + w] = s2; }
  __syncthreads();
  if (threadIdx.x == 0) {
    float ts = red[0] + red[1], ts2 = red[2] + red[3];
    const float inv = 1.0f / (16.0f * 2048.0f);
    float mean = ts * inv;
    float var = ts2 * inv - mean * mean;
    smv[0] = mean;
    smv[1] = rsqrtf(var + 1e-5f);
  }
  __syncthreads();
  const float mean = smv[0];
  const float g = gamma[c] * smv[1];
  const float bt = beta[c];
  const int t = threadIdx.x;           // 256 threads x 8 elems = 2048/row
#pragma unroll 4
  for (int b = 0; b < 16; ++b) {
    const long off = ((long)b * 1024 + c) * 2048;
    const ushortx8* yp = (const ushortx8*)(yb + off);
    const floatx4* xp = (const floatx4*)(x + off);
    floatx4* op = (floatx4*)(out + off);
    ushortx8 v8 = yp[t];
    floatx4 x0 = xp[2 * t], x1 = xp[2 * t + 1];
    floatx4 o0, o1;
#pragma unroll
    for (int r = 0; r < 4; ++r) o0[r] = (bf2f(v8[r]) - mean) * g + bt + x0[r];
#pragma unroll
    for (int r = 0; r < 4; ++r) o1[r] = (bf2f(v8[4 + r]) - mean) * g + bt + x1[r];
    op[2 * t] = o0;
    op[2 * t + 1] = o1;
  }
}

extern "C" void kernel_launch(void* const* d_in, const int* in_sizes, int n_in,
                              void* d_out, int out_size, void* d_ws, size_t ws_size,
                              hipStream_t stream) {
  (void)in_sizes; (void)n_in; (void)out_size; (void)ws_size;
  const float* x  = (const float*)d_in[0];
  const float* Wq = (const float*)d_in[1];
  const float* bq = (const float*)d_in[2];
  const float* Wk = (const float*)d_in[3];
  const float* bk = (const float*)d_in[4];
  const float* Wv = (const float*)d_in[5];
  const float* bv = (const float*)d_in[6];
  const float* Wo = (const float*)d_in[7];
  const float* bo = (const float*)d_in[8];
  const float* gamma = (const float*)d_in[9];
  const float* beta  = (const float*)d_in[10];
  float* out = (float*)d_out;

  const int Cc = 1024, T = 2048, D = 512, S = 1024;

  // Chain: prolog (transpose+convert) -> qkv (fused 256^2 8ph) ->
  // WtT = Kd V^T -> Wco = Wo WtT^T/T -> yb = bf16(Wco Qt^T + bo) with fused
  // BN partials (256^2 8ph) -> bn_apply (per-channel).
  ushort_t* ws   = (ushort_t*)d_ws;
  ushort_t* xT   = ws;                  // (B,T,C)  33,554,432
  ushort_t* Qt   = ws + 33554432;       // (B,T,D)  16,777,216
  ushort_t* KV   = ws + 50331648;       // (B,2D,S) 16,777,216
  ushort_t* WtT  = ws + 67108864;       // (B,D,D)   4,194,304
  ushort_t* Wco  = ws + 71303168;       // (B,C,D)   8,388,608
  ushort_t* yb   = ws + 79691776;       // (B,C,T)  33,554,432 bf16 pre-BN y
  ushort_t* Wq_b = ws + 113246208;      //  2,097,152 (Wq,Wk,Wv,Wo contiguous)
  ushort_t* Wo_b = ws + 113246208 + 3 * 524288;
  float*    bkv  = (float*)(ws + 115343360);    // 1024 floats
  float2*   pstat = (float2*)(ws + 115345408);  // 128*1024 float2 = 1 MB

  dim3 blk(256);
  dim3 blk512(512);

  // 0. Prologue: xT = bf16(x^T) (by<16) + weights->bf16 + bkv concat (by==16).
  prolog<<<dim3(32, 17, 16), blk, 0, stream>>>(x, xT, Wq, Wk, Wv, Wo, Wq_b,
                                               bk, bv, bkv);

  // 1. Fused Q + KV projection (768 blocks = 3 clean rounds).
  gemm_qkv<<<dim3(48, 1, 16), blk512, 0, stream>>>(xT, Wq_b, Qt, KV, bq, bkv);

  // 2. WtT (D,D) = Kd x V^T : K=S.
  gemm_bt<0, 0, false><<<dim3(D / 128, D / 128, 16), blk, 0, stream>>>(
      KV, (long)2 * D * S, KV + (long)D * S, (long)2 * D * S, WtT, (long)D * D,
      S, S, S, D, nullptr, 1.0f);
  // 3. Wco (C,D) = Wo x WtT^T / T : K=D.
  gemm_bt<0, 0, false><<<dim3(D / 128, Cc / 128, 16), blk, 0, stream>>>(
      Wo_b, 0, WtT, (long)D * D, Wco, (long)Cc * D,
      D, D, D, D, nullptr, 1.0f / 2048.0f);

  // 4. yb = bf16(Wco x Qt^T + bo), (B,C,T); fused BN partials (256^2 8-phase;
  //    R5 showed 128^2 is ~20us slower here).
  gemm256<1, 0, false, true><<<dim3(T / 256, Cc / 256, 16), blk512, 0, stream>>>(
      Wco, (long)Cc * D, Qt, (long)T * D, yb, (long)Cc * T,
      D, D, D, T, bo, 1.0f, pstat);

  // 5. BN finalize (folded) + apply + residual -> fp32 out (per-channel).
  bn_apply<<<dim3(1024), blk, 0, stream>>>(yb, x, out, pstat, gamma, beta);
}